// Round 15
// baseline (1002.640 us; speedup 1.0000x reference)
//
#include <hip/hip_runtime.h>
#include <hip/hip_bf16.h>

typedef __hip_bfloat16 bf16;
typedef __attribute__((ext_vector_type(4))) float f32x4;
typedef __attribute__((ext_vector_type(8))) short s16x8;

#define D_MODEL 768
#define N_LAYER 4
#define VOCAB 50280
#define D_STATE 16
#define D_INNER 1536
#define DT_RANK 48
#define D_CONV 4
#define BATCH 2
#define SEQ 1024
#define NTOK (BATCH * SEQ)   // 2048
#define NCHUNK 16
#define CHUNK (SEQ / NCHUNK) // 64

static __device__ __forceinline__ float bf2f(bf16 v) { return __bfloat162float(v); }
// LDS involution (verified 0-conflict rounds 4/7/8/9/10): permute 16B slot
// (bits 4-5) by row-pair bits (bits 7-8). Both-sides-or-neither (rule 21).
static __device__ __forceinline__ int swz(int b) { return b ^ (((b >> 7) & 3) << 4); }

// Pure-VALU 16-lane-group sum via DPP butterfly (verified r14).
static __device__ __forceinline__ float row16_sum(float x) {
  int v;
  v = __builtin_amdgcn_update_dpp(0, __float_as_int(x), 0xB1, 0xF, 0xF, false);
  x += __int_as_float(v);
  v = __builtin_amdgcn_update_dpp(0, __float_as_int(x), 0x4E, 0xF, 0xF, false);
  x += __int_as_float(v);
  v = __builtin_amdgcn_update_dpp(0, __float_as_int(x), 0x124, 0xF, 0xF, false);
  x += __int_as_float(v);
  v = __builtin_amdgcn_update_dpp(0, __float_as_int(x), 0x128, 0xF, 0xF, false);
  x += __int_as_float(v);
  return x;
}

// ---------------------------------------------------------------------------
// Flat f32 -> bf16 convert (vectorized), grid-stride. n must be /4.
// ---------------------------------------------------------------------------
__global__ __launch_bounds__(256) void convert_f32_bf16_kernel(
    const float* __restrict__ in, bf16* __restrict__ out, long n4) {
  long i = (long)blockIdx.x * 256 + threadIdx.x;
  long stride = (long)gridDim.x * 256;
  for (; i < n4; i += stride) {
    float4 v = ((const float4*)in)[i];
    bf16 o[4] = {__float2bfloat16(v.x), __float2bfloat16(v.y),
                 __float2bfloat16(v.z), __float2bfloat16(v.w)};
    ((ushort4*)out)[i] = *(const ushort4*)o;
  }
}

// ---------------------------------------------------------------------------
// Batched transpose + convert + row-pad: per layer z, in f32 (R,C) ->
// out bf16 (C, Rpad); rows R..Rpad-1 of the transposed output are zero.
// ---------------------------------------------------------------------------
__global__ __launch_bounds__(256) void transpose_f32_bf16_kernel(
    const float* __restrict__ in, bf16* __restrict__ out, int R, int C, int Rpad) {
  __shared__ float tile[32][33];
  const float* src = in + (size_t)blockIdx.z * R * C;
  bf16* dst = out + (size_t)blockIdx.z * C * Rpad;
  int c0 = blockIdx.x * 32, r0 = blockIdx.y * 32;
  int tx = threadIdx.x, ty = threadIdx.y;  // 32 x 8
  #pragma unroll
  for (int i = 0; i < 32; i += 8) {
    int r = r0 + ty + i, c = c0 + tx;
    if (c < C) tile[ty + i][tx] = (r < R) ? src[(size_t)r * C + c] : 0.f;
  }
  __syncthreads();
  #pragma unroll
  for (int i = 0; i < 32; i += 8) {
    int rr = c0 + ty + i, cc = r0 + tx;  // out coords (C rows, Rpad cols)
    if (rr < C && cc < Rpad) dst[(size_t)rr * Rpad + cc] = __float2bfloat16(tile[tx][ty + i]);
  }
}

// ---------------------------------------------------------------------------
// Embedding gather -> f32 residual stream
// ---------------------------------------------------------------------------
__global__ __launch_bounds__(256) void embed_kernel(
    const int* __restrict__ ids, const float* __restrict__ emb, float* __restrict__ x) {
  int m = blockIdx.x;
  int id = ids[m];
  const float* row = emb + (size_t)id * D_MODEL;
  for (int k = threadIdx.x; k < D_MODEL; k += 256)
    x[(size_t)m * D_MODEL + k] = row[k];
}

// ---------------------------------------------------------------------------
// RMSNorm: f32 row -> bf16 row (x * rsqrt(mean(x^2)+eps) * w)
// ---------------------------------------------------------------------------
__global__ __launch_bounds__(256) void rmsnorm_kernel(
    const float* __restrict__ x, const float* __restrict__ w, bf16* __restrict__ out) {
  int m = blockIdx.x;
  const float* row = x + (size_t)m * D_MODEL;
  float ss = 0.f;
  for (int k = threadIdx.x; k < D_MODEL; k += 256) { float v = row[k]; ss = fmaf(v, v, ss); }
  #pragma unroll
  for (int msk = 32; msk >= 1; msk >>= 1) ss += __shfl_xor(ss, msk);
  __shared__ float part[4];
  __shared__ float scs;
  if ((threadIdx.x & 63) == 0) part[threadIdx.x >> 6] = ss;
  __syncthreads();
  if (threadIdx.x == 0) {
    float tot = part[0] + part[1] + part[2] + part[3];
    scs = rsqrtf(tot / (float)D_MODEL + 1e-5f);
  }
  __syncthreads();
  float scale = scs;
  for (int k = threadIdx.x; k < D_MODEL; k += 256)
    out[(size_t)m * D_MODEL + k] = __float2bfloat16(row[k] * scale * w[k]);
}

// ---------------------------------------------------------------------------
// GEMM (128x128 tile, 3-buffer depth-3 counted-vmcnt pipeline):
// C = A[M,K] @ BT[N,K]^T. m-fastest 1D grid + bijective XCD chunking.
// Buffers hold stages t, t+1, t+2 (buffer = stage%3). Per K-step:
//   wait vmcnt(8) (stage t done; t+1,t+2's 8 loads stay in flight)
//   -> barrier -> compute -> barrier -> stage(t+3 into t%3).
// Depth-3 covers ~900cy HBM-miss latency of the 64B/row scattered B reads.
// EPI: 0 = store f32 via LDS-staged dwordx4, 3 = store bf16 scalar.
// ---------------------------------------------------------------------------
template <int EPI>
__global__ __launch_bounds__(256) void gemm128_kernel(
    const bf16* __restrict__ A, const bf16* __restrict__ BT,
    float* __restrict__ Cf, bf16* __restrict__ Cb, int M, int N, int K) {
  const int nm = M >> 7;
  const int total = gridDim.x;
  const int q = total >> 3, r = total & 7;
  int lin = blockIdx.x;
  int xcd = lin & 7, off = lin >> 3;
  int sw = (xcd < r ? xcd * (q + 1) : r * (q + 1) + (xcd - r) * q) + off;
  const int m0 = (sw % nm) * 128, n0 = (sw / nm) * 128;

  const int tid = threadIdx.x, lane = tid & 63, w = tid >> 6;
  const int wr = w >> 1, wc = w & 1;
  const int r16 = lane & 15, kc = lane >> 4;

  __shared__ __attribute__((aligned(16))) bf16 As[3][128 * 32];
  __shared__ __attribute__((aligned(16))) bf16 Bs[3][128 * 32];

  f32x4 acc[4][4];
  #pragma unroll
  for (int i = 0; i < 4; ++i)
    #pragma unroll
    for (int j = 0; j < 4; ++j) acc[i][j] = (f32x4){0.f, 0.f, 0.f, 0.f};

  auto stage = [&](int buf, int k0) {
    #pragma unroll
    for (int i = 0; i < 2; ++i) {
      int o = i * 4096 + w * 1024 + lane * 16;  // byte offset in 8KB tile
      int row = o >> 6, cb = swz(o) & 63;       // pre-swizzled source slot
      const char* gA = (const char*)A + ((size_t)(m0 + row) * K + k0) * 2 + cb;
      int gn = n0 + row; if (gn > N - 1) gn = N - 1;
      const char* gB = (const char*)BT + ((size_t)gn * K + k0) * 2 + cb;
      __builtin_amdgcn_global_load_lds(
          (const __attribute__((address_space(1))) void*)gA,
          (__attribute__((address_space(3))) void*)((char*)As[buf] + i * 4096 + w * 1024), 16, 0, 0);
      __builtin_amdgcn_global_load_lds(
          (const __attribute__((address_space(1))) void*)gB,
          (__attribute__((address_space(3))) void*)((char*)Bs[buf] + i * 4096 + w * 1024), 16, 0, 0);
    }
  };

  const int nk = K >> 5;
  stage(0, 0);
  if (nk > 1) stage(1, 32);
  if (nk > 2) stage(2, 64);
  int cur = 0;
  for (int t = 0; t < nk; ++t) {
    if (t + 2 < nk)      asm volatile("s_waitcnt vmcnt(8)" ::: "memory");
    else if (t + 1 < nk) asm volatile("s_waitcnt vmcnt(4)" ::: "memory");
    else                 asm volatile("s_waitcnt vmcnt(0)" ::: "memory");
    __builtin_amdgcn_s_barrier();

    s16x8 af[4], bfr[4];
    #pragma unroll
    for (int mi = 0; mi < 4; ++mi) {
      int row = wr * 64 + mi * 16 + r16;
      af[mi] = *(const s16x8*)((const char*)As[cur] + swz(row * 64 + kc * 16));
    }
    #pragma unroll
    for (int ni = 0; ni < 4; ++ni) {
      int row = wc * 64 + ni * 16 + r16;
      bfr[ni] = *(const s16x8*)((const char*)Bs[cur] + swz(row * 64 + kc * 16));
    }
    #pragma unroll
    for (int mi = 0; mi < 4; ++mi)
      #pragma unroll
      for (int ni = 0; ni < 4; ++ni)
        acc[mi][ni] = __builtin_amdgcn_mfma_f32_16x16x32_bf16(af[mi], bfr[ni], acc[mi][ni], 0, 0, 0);

    asm volatile("" ::: "memory");          // pin ds_reads above the barrier
    __builtin_amdgcn_s_barrier();           // all waves done reading buf cur
    if (t + 3 < nk) stage(cur, (t + 3) << 5);
    cur = (cur == 2) ? 0 : cur + 1;
  }

  if (EPI == 0) {
    // Coalesced epilogue: per-wave 4KB LDS slice (reusing As; wave-local).
    char* ws_ = (char*)&As[0][0] + w * 4096;
    #pragma unroll
    for (int mi = 0; mi < 4; ++mi) {
      #pragma unroll
      for (int ni = 0; ni < 4; ++ni)
        #pragma unroll
        for (int j = 0; j < 4; ++j)
          *(float*)(ws_ + ((kc * 4 + j) * 64 + ni * 16 + r16) * 4) = acc[mi][ni][j];
      asm volatile("s_waitcnt lgkmcnt(0)" ::: "memory");
      #pragma unroll
      for (int i = 0; i < 4; ++i) {
        int o = i * 1024 + lane * 16;       // byte offset in 4KB slice
        float4 v = *(const float4*)(ws_ + o);
        int row = o >> 8;                   // /256B -> local row 0..15
        int cg = n0 + wc * 64 + ((o & 255) >> 2);
        int rg = m0 + wr * 64 + mi * 16 + row;
        if (cg < N)                         // N%4==0 && cg%4==0 -> full f4 ok
          *(float4*)(Cf + (size_t)rg * N + cg) = v;
      }
      asm volatile("s_waitcnt lgkmcnt(0)" ::: "memory");
    }
  } else {
    #pragma unroll
    for (int mi = 0; mi < 4; ++mi) {
      #pragma unroll
      for (int ni = 0; ni < 4; ++ni) {
        int col = n0 + wc * 64 + ni * 16 + r16;
        if (col < N) {
          #pragma unroll
          for (int j = 0; j < 4; ++j) {
            int rowg = m0 + wr * 64 + mi * 16 + kc * 4 + j;
            Cb[(size_t)rowg * N + col] = __float2bfloat16(acc[mi][ni][j]);
          }
        }
      }
    }
  }
}

// ---------------------------------------------------------------------------
// Layer GEMM (64x64 tile, double-buffered, plain __syncthreads):
// C[M,N] = A[M,K] @ BT[N,K]^T.
// EPI: 1 = accumulate into f32, 2 = softplus(v + bias[col]) f32.
// ---------------------------------------------------------------------------
template <int EPI>
__global__ __launch_bounds__(256) void gemm64_kernel(
    const bf16* __restrict__ A, const bf16* __restrict__ BT,
    float* __restrict__ Cf, const float* __restrict__ bias, int M, int N, int K) {
  const int nm = M >> 6;
  const int m0 = (blockIdx.x % nm) * 64, n0 = (blockIdx.x / nm) * 64;
  const int tid = threadIdx.x, lane = tid & 63, w = tid >> 6;
  const int wr = w >> 1, wc = w & 1;
  const int r16 = lane & 15, kc = lane >> 4;

  __shared__ __attribute__((aligned(16))) bf16 As[2][64 * 32];
  __shared__ __attribute__((aligned(16))) bf16 Bs[2][64 * 32];

  f32x4 acc[2][2];
  #pragma unroll
  for (int i = 0; i < 2; ++i)
    #pragma unroll
    for (int j = 0; j < 2; ++j) acc[i][j] = (f32x4){0.f, 0.f, 0.f, 0.f};

  auto stage = [&](int buf, int k0) {
    int o = tid * 16;                       // byte offset in 4KB tile
    int row = o >> 6, cb = swz(o) & 63;
    const char* gA = (const char*)A + ((size_t)(m0 + row) * K + k0) * 2 + cb;
    const char* gB = (const char*)BT + ((size_t)(n0 + row) * K + k0) * 2 + cb;
    __builtin_amdgcn_global_load_lds(
        (const __attribute__((address_space(1))) void*)gA,
        (__attribute__((address_space(3))) void*)((char*)As[buf] + w * 1024), 16, 0, 0);
    __builtin_amdgcn_global_load_lds(
        (const __attribute__((address_space(1))) void*)gB,
        (__attribute__((address_space(3))) void*)((char*)Bs[buf] + w * 1024), 16, 0, 0);
  };

  const int nk = K >> 5;
  stage(0, 0);
  __syncthreads();
  int cur = 0;
  for (int t = 0; t < nk; ++t) {
    if (t + 1 < nk) stage(cur ^ 1, (t + 1) << 5);
    s16x8 af[2], bfr[2];
    #pragma unroll
    for (int mi = 0; mi < 2; ++mi) {
      int row = wr * 32 + mi * 16 + r16;
      af[mi] = *(const s16x8*)((const char*)As[cur] + swz(row * 64 + kc * 16));
    }
    #pragma unroll
    for (int ni = 0; ni < 2; ++ni) {
      int row = wc * 32 + ni * 16 + r16;
      bfr[ni] = *(const s16x8*)((const char*)Bs[cur] + swz(row * 64 + kc * 16));
    }
    #pragma unroll
    for (int mi = 0; mi < 2; ++mi)
      #pragma unroll
      for (int ni = 0; ni < 2; ++ni)
        acc[mi][ni] = __builtin_amdgcn_mfma_f32_16x16x32_bf16(af[mi], bfr[ni], acc[mi][ni], 0, 0, 0);
    __syncthreads();
    cur ^= 1;
  }

  #pragma unroll
  for (int mi = 0; mi < 2; ++mi) {
    #pragma unroll
    for (int ni = 0; ni < 2; ++ni) {
      int col = n0 + wc * 32 + ni * 16 + r16;
      #pragma unroll
      for (int j = 0; j < 4; ++j) {
        int rowg = m0 + wr * 32 + mi * 16 + kc * 4 + j;
        size_t idx = (size_t)rowg * N + col;
        float v = acc[mi][ni][j];
        if (EPI == 1) Cf[idx] += v;
        else {
          float t = v + bias[col];
          Cf[idx] = (t > 20.f) ? t : log1pf(__expf(t));
        }
      }
    }
  }
}

// ---------------------------------------------------------------------------
// Depthwise causal conv (k=4) + bias + silu -> ubf. xz bf16 (NTOK, 3072).
// ---------------------------------------------------------------------------
__global__ __launch_bounds__(256) void conv_silu_kernel(
    const bf16* __restrict__ xzb, const float* __restrict__ cw, const float* __restrict__ cb,
    bf16* __restrict__ ubf) {
  int m = blockIdx.x;
  int d = blockIdx.y * 256 + threadIdx.x;
  int s = m & (SEQ - 1);
  float acc = cb[d];
  #pragma unroll
  for (int j = 0; j < D_CONV; ++j) {
    int sj = s - 3 + j;
    if (sj >= 0) acc += bf2f(xzb[(size_t)(m - 3 + j) * (2 * D_INNER) + d]) * cw[d * D_CONV + j];
  }
  float sv = acc / (1.f + __expf(-acc));
  ubf[(size_t)m * D_INNER + d] = __float2bfloat16(sv);
}

// ---------------------------------------------------------------------------
// x_proj as skinny MFMA GEMM: xdbl[M=2048, 80] = ubf @ xpwT^T (xpwT (80,1536)).
// Block = 16 tokens; 4 waves split K (each 384, 12 K-steps x 5 MFMA);
// cross-wave reduce in LDS. Also emits dlt bf16 zero-padded to (NTOK, 64).
// ---------------------------------------------------------------------------
__global__ __launch_bounds__(256) void xproj_mfma_kernel(
    const bf16* __restrict__ ubf, const bf16* __restrict__ xpwT,
    float* __restrict__ xdbl, bf16* __restrict__ dltb) {
  const int m0 = blockIdx.x * 16;
  const int tid = threadIdx.x, lane = tid & 63, w = tid >> 6;
  const int r16 = lane & 15, kc = lane >> 4;
  __shared__ float part[4][16][80];  // 20 KB

  f32x4 acc[5];
  #pragma unroll
  for (int ni = 0; ni < 5; ++ni) acc[ni] = (f32x4){0.f, 0.f, 0.f, 0.f};

  const char* aBase = (const char*)ubf + (size_t)(m0 + r16) * 3072;
  #pragma unroll 4
  for (int kk = 0; kk < 12; ++kk) {
    int koff = (w * 384 + kk * 32) * 2 + kc * 16;
    s16x8 a = *(const s16x8*)(aBase + koff);
    #pragma unroll
    for (int ni = 0; ni < 5; ++ni) {
      s16x8 b = *(const s16x8*)((const char*)xpwT + (size_t)(ni * 16 + r16) * 3072 + koff);
      acc[ni] = __builtin_amdgcn_mfma_f32_16x16x32_bf16(a, b, acc[ni], 0, 0, 0);
    }
  }
  #pragma unroll
  for (int ni = 0; ni < 5; ++ni)
    #pragma unroll
    for (int j = 0; j < 4; ++j)
      part[w][kc * 4 + j][ni * 16 + r16] = acc[ni][j];
  __syncthreads();

  for (int i = tid; i < 16 * 80; i += 256) {
    int row = i / 80, col = i - row * 80;
    float s = part[0][row][col] + part[1][row][col] +
              part[2][row][col] + part[3][row][col];
    xdbl[(size_t)(m0 + row) * 80 + col] = s;
    if (col < DT_RANK) dltb[(size_t)(m0 + row) * 64 + col] = __float2bfloat16(s);
  }
  {  // zero-pad dlt cols 48..63 (16x16 = 256 elems, one per thread)
    int row = tid >> 4, k = DT_RANK + (tid & 15);
    dltb[(size_t)(m0 + row) * 64 + k] = __float2bfloat16(0.f);
  }
}

// ---------------------------------------------------------------------------
// Chunked parallel selective scan, LDS-staged (r13/r14 structure).
// PASS 0: from x=0, chunk summary (Aprod, xpart).
// PASS 1: fold chunk-prefix inline, then emit y*silu(res); per-step 16-lane
// reduction via pure-VALU DPP butterfly (row16_sum).
// ---------------------------------------------------------------------------
template <int PASS>
__global__ __launch_bounds__(256) void scan_chunk_kernel(
    const float* __restrict__ delta, const bf16* __restrict__ ubf,
    const float* __restrict__ xdbl, const bf16* __restrict__ xzb,
    const float* __restrict__ A_log, const float* __restrict__ Dvec,
    float* __restrict__ Aprod, float* __restrict__ xpart,
    bf16* __restrict__ ybf) {
  int bd = blockIdx.x;  // 0 .. BATCH*96-1
  int c = blockIdx.y;
  int b = bd / (D_INNER / 16), dblk = bd % (D_INNER / 16);
  int grp = threadIdx.x >> 4, n = threadIdx.x & 15;
  int d = dblk * 16 + grp;
  const int d0 = dblk * 16;
  const size_t cstride = (size_t)BATCH * D_INNER * D_STATE;
  size_t si0 = ((size_t)b * D_INNER + d) * 16 + n;
  size_t mbase = (size_t)b * SEQ + (size_t)c * CHUNK;

  __shared__ float sd[CHUNK][16];                 // delta slice, 4KB
  __shared__ float su[CHUNK][16];                 // u slice, 4KB
  __shared__ float sB[CHUNK][16];                 // B_t, 4KB
  __shared__ float sC[PASS ? CHUNK : 1][16];      // C_t (pass1)
  __shared__ float sz[PASS ? CHUNK : 1][16];      // res (pass1)

  for (int i = threadIdx.x; i < CHUNK * 16; i += 256) {
    int t = i >> 4, dd = i & 15;
    size_t m = mbase + t;
    sd[t][dd] = delta[m * D_INNER + d0 + dd];
    su[t][dd] = bf2f(ubf[m * D_INNER + d0 + dd]);
    sB[t][dd] = xdbl[m * 80 + DT_RANK + dd];
    if (PASS == 1) {
      sC[t][dd] = xdbl[m * 80 + DT_RANK + D_STATE + dd];
      sz[t][dd] = bf2f(xzb[m * (2 * D_INNER) + D_INNER + d0 + dd]);
    }
  }
  __syncthreads();

  float Adn = -__expf(A_log[(size_t)d * D_STATE + n]);
  float Dd = Dvec[d];
  float xs = 0.f;
  if (PASS == 1) {
    for (int cc = 0; cc < c; ++cc)
      xs = fmaf(Aprod[cc * cstride + si0], xs, xpart[cc * cstride + si0]);
  }
  float ap = 1.f;
  #pragma unroll 4
  for (int t = 0; t < CHUNK; ++t) {
    float dlt = sd[t][grp];
    float uv = su[t][grp];
    float Bv = sB[t][n];
    float a = __expf(dlt * Adn);
    xs = fmaf(a, xs, dlt * Bv * uv);
    if (PASS == 0) {
      ap *= a;
    } else {
      float p = row16_sum(xs * sC[t][n]);
      if (n == 0) {
        float rv = sz[t][grp];
        float y = p + uv * Dd;
        float g = rv / (1.f + __expf(-rv));
        ybf[(mbase + t) * D_INNER + d] = __float2bfloat16(y * g);
      }
    }
  }
  if (PASS == 0) {
    Aprod[c * cstride + si0] = ap;
    xpart[c * cstride + si0] = xs;
  }
}

// ---------------------------------------------------------------------------
extern "C" void kernel_launch(void* const* d_in, const int* in_sizes, int n_in,
                              void* d_out, int out_size, void* d_ws, size_t ws_size,
                              hipStream_t stream) {
  const int* ids = (const int*)d_in[0];
  const float* emb = (const float*)d_in[1];     // (VOCAB, 768)
  const float* in_w = (const float*)d_in[2];    // (L, 768, 3072)
  const float* conv_w = (const float*)d_in[3];  // (L, 1536, 4)
  const float* conv_b = (const float*)d_in[4];  // (L, 1536)
  const float* xp_w = (const float*)d_in[5];    // (L, 1536, 80)
  const float* dt_w = (const float*)d_in[6];    // (L, 48, 1536)
  const float* dt_b = (const float*)d_in[7];    // (L, 1536)
  const float* A_log = (const float*)d_in[8];   // (L, 1536, 16)
  const float* Dv = (const float*)d_in[9];      // (L, 1536)
  const float* out_w = (const float*)d_in[10];  // (L, 1536, 768)
  const float* norm_w = (const float*)d_in[11]; // (L, 768)
  const float* norm_f = (const float*)d_in[12]; // (768)
  float* out = (float*)d_out;                   // (NTOK, VOCAB) f32

  // workspace carve
  char* p = (char*)d_ws;
  auto alloc = [&](size_t bytes) {
    char* r = p;
    p += (bytes + 255) & ~(size_t)255;
    return r;
  };
  float* x    = (float*)alloc((size_t)NTOK * D_MODEL * 4);
  bf16*  h    = (bf16*)alloc((size_t)NTOK * D_MODEL * 2);
  bf16*  xn   = (bf16*)alloc((size_t)NTOK * D_MODEL * 2);
  bf16*  xzb  = (bf16*)alloc((size_t)NTOK * 2 * D_INNER * 2);
  bf16*  ubf  = (bf16*)alloc((size_t)NTOK * D_INNER * 2);
  float* xdbl = (float*)alloc((size_t)NTOK * 80 * 4);
  bf16*  dltb = (bf16*)alloc((size_t)NTOK * 64 * 2);
  float* delta= (float*)alloc((size_t)NTOK * D_INNER * 4);
  bf16*  ybf  = (bf16*)alloc((size_t)NTOK * D_INNER * 2);
  float* Aprod= (float*)alloc((size_t)NCHUNK * BATCH * D_INNER * D_STATE * 4);
  float* xpart= (float*)alloc((size_t)NCHUNK * BATCH * D_INNER * D_STATE * 4);
  bf16*  in_wT  = (bf16*)alloc((size_t)N_LAYER * 2 * D_INNER * D_MODEL * 2);
  bf16*  out_wT = (bf16*)alloc((size_t)N_LAYER * D_MODEL * D_INNER * 2);
  bf16*  xp_wT  = (bf16*)alloc((size_t)N_LAYER * 80 * D_INNER * 2);
  bf16*  dt_wT  = (bf16*)alloc((size_t)N_LAYER * D_INNER * 64 * 2);
  bf16*  emb_bf = (bf16*)alloc((size_t)VOCAB * D_MODEL * 2);

  // Weight prep
  dim3 tb(32, 8);
  convert_f32_bf16_kernel<<<8192, 256, 0, stream>>>(
      emb, emb_bf, (long)VOCAB * D_MODEL / 4);
  transpose_f32_bf16_kernel<<<dim3(3072 / 32, 768 / 32, N_LAYER), tb, 0, stream>>>(
      in_w, in_wT, D_MODEL, 2 * D_INNER, D_MODEL);
  transpose_f32_bf16_kernel<<<dim3(768 / 32, 1536 / 32, N_LAYER), tb, 0, stream>>>(
      out_w, out_wT, D_INNER, D_MODEL, D_INNER);
  transpose_f32_bf16_kernel<<<dim3(3, 1536 / 32, N_LAYER), tb, 0, stream>>>(
      xp_w, xp_wT, D_INNER, 80, D_INNER);
  // dt_w (48,1536) -> (1536,64) zero-padded
  transpose_f32_bf16_kernel<<<dim3(1536 / 32, 2, N_LAYER), tb, 0, stream>>>(
      dt_w, dt_wT, DT_RANK, D_INNER, 64);

  embed_kernel<<<NTOK, 256, 0, stream>>>(ids, emb, x);

  for (int l = 0; l < N_LAYER; ++l) {
    const bf16* inwT_l = in_wT + (size_t)l * 2 * D_INNER * D_MODEL;
    const bf16* outwT_l = out_wT + (size_t)l * D_MODEL * D_INNER;
    const bf16* xpwT_l = xp_wT + (size_t)l * 80 * D_INNER;
    const bf16* dtwT_l = dt_wT + (size_t)l * D_INNER * 64;
    const float* Al = A_log + (size_t)l * D_INNER * D_STATE;
    const float* Dl = Dv + (size_t)l * D_INNER;

    rmsnorm_kernel<<<NTOK, 256, 0, stream>>>(x, norm_w + (size_t)l * D_MODEL, h);

    // in_proj: 128x128 depth-3 GEMM, bf16 store into xzb
    gemm128_kernel<3><<<(NTOK / 128) * (2 * D_INNER / 128), 256, 0, stream>>>(
        h, inwT_l, nullptr, xzb, NTOK, 2 * D_INNER, D_MODEL);

    conv_silu_kernel<<<dim3(NTOK, D_INNER / 256), 256, 0, stream>>>(
        xzb, conv_w + (size_t)l * D_INNER * D_CONV, conv_b + (size_t)l * D_INNER, ubf);

    xproj_mfma_kernel<<<NTOK / 16, 256, 0, stream>>>(ubf, xpwT_l, xdbl, dltb);

    gemm64_kernel<2><<<(NTOK / 64) * (D_INNER / 64), 256, 0, stream>>>(
        dltb, dtwT_l, delta, dt_b + (size_t)l * D_INNER, NTOK, D_INNER, 64);

    dim3 sgrid(BATCH * (D_INNER / 16), NCHUNK);
    scan_chunk_kernel<0><<<sgrid, 256, 0, stream>>>(
        delta, ubf, xdbl, xzb, Al, Dl, Aprod, xpart, nullptr);
    scan_chunk_kernel<1><<<sgrid, 256, 0, stream>>>(
        delta, ubf, xdbl, xzb, Al, Dl, Aprod, xpart, ybf);

    gemm64_kernel<1><<<(NTOK / 64) * (D_MODEL / 64), 256, 0, stream>>>(
        ybf, outwT_l, x, nullptr, NTOK, D_MODEL, D_INNER);
  }

  rmsnorm_kernel<<<NTOK, 256, 0, stream>>>(x, norm_f, xn);

  gemm128_kernel<0><<<(NTOK / 128) * ((VOCAB + 127) / 128), 256, 0, stream>>>(
      xn, emb_bf, out, nullptr, NTOK, VOCAB, D_MODEL);
}

// Round 17
// 984.120 us; speedup vs baseline: 1.0188x; 1.0188x over previous
//
#include <hip/hip_runtime.h>
#include <hip/hip_bf16.h>

typedef __hip_bfloat16 bf16;
typedef __attribute__((ext_vector_type(4))) float f32x4;
typedef __attribute__((ext_vector_type(8))) short s16x8;

#define D_MODEL 768
#define N_LAYER 4
#define VOCAB 50280
#define D_STATE 16
#define D_INNER 1536
#define DT_RANK 48
#define D_CONV 4
#define BATCH 2
#define SEQ 1024
#define NTOK (BATCH * SEQ)   // 2048
#define NCHUNK 16
#define CHUNK (SEQ / NCHUNK) // 64

static __device__ __forceinline__ float bf2f(bf16 v) { return __bfloat162float(v); }
// LDS involution (verified 0-conflict rounds 4/7/8/9/10): permute 16B slot
// (bits 4-5) by row-pair bits (bits 7-8). Both-sides-or-neither (rule 21).
static __device__ __forceinline__ int swz(int b) { return b ^ (((b >> 7) & 3) << 4); }

// Pure-VALU 16-lane-group sum via DPP butterfly (verified r14).
static __device__ __forceinline__ float row16_sum(float x) {
  int v;
  v = __builtin_amdgcn_update_dpp(0, __float_as_int(x), 0xB1, 0xF, 0xF, false);
  x += __int_as_float(v);
  v = __builtin_amdgcn_update_dpp(0, __float_as_int(x), 0x4E, 0xF, 0xF, false);
  x += __int_as_float(v);
  v = __builtin_amdgcn_update_dpp(0, __float_as_int(x), 0x124, 0xF, 0xF, false);
  x += __int_as_float(v);
  v = __builtin_amdgcn_update_dpp(0, __float_as_int(x), 0x128, 0xF, 0xF, false);
  x += __int_as_float(v);
  return x;
}

// ---------------------------------------------------------------------------
// Flat f32 -> bf16 convert (vectorized), grid-stride. n must be /4.
// ---------------------------------------------------------------------------
__global__ __launch_bounds__(256) void convert_f32_bf16_kernel(
    const float* __restrict__ in, bf16* __restrict__ out, long n4) {
  long i = (long)blockIdx.x * 256 + threadIdx.x;
  long stride = (long)gridDim.x * 256;
  for (; i < n4; i += stride) {
    float4 v = ((const float4*)in)[i];
    bf16 o[4] = {__float2bfloat16(v.x), __float2bfloat16(v.y),
                 __float2bfloat16(v.z), __float2bfloat16(v.w)};
    ((ushort4*)out)[i] = *(const ushort4*)o;
  }
}

// ---------------------------------------------------------------------------
// Batched transpose + convert + row-pad: per layer z, in f32 (R,C) ->
// out bf16 (C, Rpad); rows R..Rpad-1 of the transposed output are zero.
// ---------------------------------------------------------------------------
__global__ __launch_bounds__(256) void transpose_f32_bf16_kernel(
    const float* __restrict__ in, bf16* __restrict__ out, int R, int C, int Rpad) {
  __shared__ float tile[32][33];
  const float* src = in + (size_t)blockIdx.z * R * C;
  bf16* dst = out + (size_t)blockIdx.z * C * Rpad;
  int c0 = blockIdx.x * 32, r0 = blockIdx.y * 32;
  int tx = threadIdx.x, ty = threadIdx.y;  // 32 x 8
  #pragma unroll
  for (int i = 0; i < 32; i += 8) {
    int r = r0 + ty + i, c = c0 + tx;
    if (c < C) tile[ty + i][tx] = (r < R) ? src[(size_t)r * C + c] : 0.f;
  }
  __syncthreads();
  #pragma unroll
  for (int i = 0; i < 32; i += 8) {
    int rr = c0 + ty + i, cc = r0 + tx;  // out coords (C rows, Rpad cols)
    if (rr < C && cc < Rpad) dst[(size_t)rr * Rpad + cc] = __float2bfloat16(tile[tx][ty + i]);
  }
}

// ---------------------------------------------------------------------------
// Embedding gather -> f32 residual stream
// ---------------------------------------------------------------------------
__global__ __launch_bounds__(256) void embed_kernel(
    const int* __restrict__ ids, const float* __restrict__ emb, float* __restrict__ x) {
  int m = blockIdx.x;
  int id = ids[m];
  const float* row = emb + (size_t)id * D_MODEL;
  for (int k = threadIdx.x; k < D_MODEL; k += 256)
    x[(size_t)m * D_MODEL + k] = row[k];
}

// ---------------------------------------------------------------------------
// RMSNorm: f32 row -> bf16 row (x * rsqrt(mean(x^2)+eps) * w)
// ---------------------------------------------------------------------------
__global__ __launch_bounds__(256) void rmsnorm_kernel(
    const float* __restrict__ x, const float* __restrict__ w, bf16* __restrict__ out) {
  int m = blockIdx.x;
  const float* row = x + (size_t)m * D_MODEL;
  float ss = 0.f;
  for (int k = threadIdx.x; k < D_MODEL; k += 256) { float v = row[k]; ss = fmaf(v, v, ss); }
  #pragma unroll
  for (int msk = 32; msk >= 1; msk >>= 1) ss += __shfl_xor(ss, msk);
  __shared__ float part[4];
  __shared__ float scs;
  if ((threadIdx.x & 63) == 0) part[threadIdx.x >> 6] = ss;
  __syncthreads();
  if (threadIdx.x == 0) {
    float tot = part[0] + part[1] + part[2] + part[3];
    scs = rsqrtf(tot / (float)D_MODEL + 1e-5f);
  }
  __syncthreads();
  float scale = scs;
  for (int k = threadIdx.x; k < D_MODEL; k += 256)
    out[(size_t)m * D_MODEL + k] = __float2bfloat16(row[k] * scale * w[k]);
}

// ---------------------------------------------------------------------------
// GEMM (128x128 tile, 2-buffer counted-vmcnt, verified r9/r10/r14 @258us):
// C = A[M,K] @ BT[N,K]^T. m-fastest 1D grid + bijective XCD chunking.
// Per K-step: vmcnt(4) + barrier -> compute -> barrier -> stage t+2.
// EPI: 0 = store f32 via LDS-staged dwordx4, 3 = store bf16 scalar.
// ---------------------------------------------------------------------------
template <int EPI>
__global__ __launch_bounds__(256) void gemm128_kernel(
    const bf16* __restrict__ A, const bf16* __restrict__ BT,
    float* __restrict__ Cf, bf16* __restrict__ Cb, int M, int N, int K) {
  const int nm = M >> 7;
  const int total = gridDim.x;
  const int q = total >> 3, r = total & 7;
  int lin = blockIdx.x;
  int xcd = lin & 7, off = lin >> 3;
  int sw = (xcd < r ? xcd * (q + 1) : r * (q + 1) + (xcd - r) * q) + off;
  const int m0 = (sw % nm) * 128, n0 = (sw / nm) * 128;

  const int tid = threadIdx.x, lane = tid & 63, w = tid >> 6;
  const int wr = w >> 1, wc = w & 1;
  const int r16 = lane & 15, kc = lane >> 4;

  __shared__ __attribute__((aligned(16))) bf16 As[2][128 * 32];
  __shared__ __attribute__((aligned(16))) bf16 Bs[2][128 * 32];

  f32x4 acc[4][4];
  #pragma unroll
  for (int i = 0; i < 4; ++i)
    #pragma unroll
    for (int j = 0; j < 4; ++j) acc[i][j] = (f32x4){0.f, 0.f, 0.f, 0.f};

  auto stage = [&](int buf, int k0) {
    #pragma unroll
    for (int i = 0; i < 2; ++i) {
      int o = i * 4096 + w * 1024 + lane * 16;  // byte offset in 8KB tile
      int row = o >> 6, cb = swz(o) & 63;       // pre-swizzled source slot
      const char* gA = (const char*)A + ((size_t)(m0 + row) * K + k0) * 2 + cb;
      int gn = n0 + row; if (gn > N - 1) gn = N - 1;
      const char* gB = (const char*)BT + ((size_t)gn * K + k0) * 2 + cb;
      __builtin_amdgcn_global_load_lds(
          (const __attribute__((address_space(1))) void*)gA,
          (__attribute__((address_space(3))) void*)((char*)As[buf] + i * 4096 + w * 1024), 16, 0, 0);
      __builtin_amdgcn_global_load_lds(
          (const __attribute__((address_space(1))) void*)gB,
          (__attribute__((address_space(3))) void*)((char*)Bs[buf] + i * 4096 + w * 1024), 16, 0, 0);
    }
  };

  const int nk = K >> 5;
  stage(0, 0);
  if (nk > 1) stage(1, 32);
  int cur = 0;
  for (int t = 0; t < nk; ++t) {
    if (t + 1 < nk) asm volatile("s_waitcnt vmcnt(4)" ::: "memory");
    else            asm volatile("s_waitcnt vmcnt(0)" ::: "memory");
    __builtin_amdgcn_s_barrier();

    s16x8 af[4], bfr[4];
    #pragma unroll
    for (int mi = 0; mi < 4; ++mi) {
      int row = wr * 64 + mi * 16 + r16;
      af[mi] = *(const s16x8*)((const char*)As[cur] + swz(row * 64 + kc * 16));
    }
    #pragma unroll
    for (int ni = 0; ni < 4; ++ni) {
      int row = wc * 64 + ni * 16 + r16;
      bfr[ni] = *(const s16x8*)((const char*)Bs[cur] + swz(row * 64 + kc * 16));
    }
    #pragma unroll
    for (int mi = 0; mi < 4; ++mi)
      #pragma unroll
      for (int ni = 0; ni < 4; ++ni)
        acc[mi][ni] = __builtin_amdgcn_mfma_f32_16x16x32_bf16(af[mi], bfr[ni], acc[mi][ni], 0, 0, 0);

    asm volatile("" ::: "memory");          // pin ds_reads above the barrier
    __builtin_amdgcn_s_barrier();           // all waves done reading buf cur
    if (t + 2 < nk) stage(cur, (t + 2) << 5);
    cur ^= 1;
  }

  if (EPI == 0) {
    // Coalesced epilogue: per-wave 4KB LDS slice (reusing As; wave-local).
    char* ws_ = (char*)&As[0][0] + w * 4096;
    #pragma unroll
    for (int mi = 0; mi < 4; ++mi) {
      #pragma unroll
      for (int ni = 0; ni < 4; ++ni)
        #pragma unroll
        for (int j = 0; j < 4; ++j)
          *(float*)(ws_ + ((kc * 4 + j) * 64 + ni * 16 + r16) * 4) = acc[mi][ni][j];
      asm volatile("s_waitcnt lgkmcnt(0)" ::: "memory");
      #pragma unroll
      for (int i = 0; i < 4; ++i) {
        int o = i * 1024 + lane * 16;       // byte offset in 4KB slice
        float4 v = *(const float4*)(ws_ + o);
        int row = o >> 8;                   // /256B -> local row 0..15
        int cg = n0 + wc * 64 + ((o & 255) >> 2);
        int rg = m0 + wr * 64 + mi * 16 + row;
        if (cg < N)                         // N%4==0 && cg%4==0 -> full f4 ok
          *(float4*)(Cf + (size_t)rg * N + cg) = v;
      }
      asm volatile("s_waitcnt lgkmcnt(0)" ::: "memory");
    }
  } else {
    #pragma unroll
    for (int mi = 0; mi < 4; ++mi) {
      #pragma unroll
      for (int ni = 0; ni < 4; ++ni) {
        int col = n0 + wc * 64 + ni * 16 + r16;
        if (col < N) {
          #pragma unroll
          for (int j = 0; j < 4; ++j) {
            int rowg = m0 + wr * 64 + mi * 16 + kc * 4 + j;
            Cb[(size_t)rowg * N + col] = __float2bfloat16(acc[mi][ni][j]);
          }
        }
      }
    }
  }
}

// ---------------------------------------------------------------------------
// Layer GEMM (64x64 tile, double-buffered, plain __syncthreads):
// C[M,N] = A[M,K] @ BT[N,K]^T.
// EPI: 1 = accumulate into f32, 2 = softplus(v + bias[col]) f32.
// ---------------------------------------------------------------------------
template <int EPI>
__global__ __launch_bounds__(256) void gemm64_kernel(
    const bf16* __restrict__ A, const bf16* __restrict__ BT,
    float* __restrict__ Cf, const float* __restrict__ bias, int M, int N, int K) {
  const int nm = M >> 6;
  const int m0 = (blockIdx.x % nm) * 64, n0 = (blockIdx.x / nm) * 64;
  const int tid = threadIdx.x, lane = tid & 63, w = tid >> 6;
  const int wr = w >> 1, wc = w & 1;
  const int r16 = lane & 15, kc = lane >> 4;

  __shared__ __attribute__((aligned(16))) bf16 As[2][64 * 32];
  __shared__ __attribute__((aligned(16))) bf16 Bs[2][64 * 32];

  f32x4 acc[2][2];
  #pragma unroll
  for (int i = 0; i < 2; ++i)
    #pragma unroll
    for (int j = 0; j < 2; ++j) acc[i][j] = (f32x4){0.f, 0.f, 0.f, 0.f};

  auto stage = [&](int buf, int k0) {
    int o = tid * 16;                       // byte offset in 4KB tile
    int row = o >> 6, cb = swz(o) & 63;
    const char* gA = (const char*)A + ((size_t)(m0 + row) * K + k0) * 2 + cb;
    const char* gB = (const char*)BT + ((size_t)(n0 + row) * K + k0) * 2 + cb;
    __builtin_amdgcn_global_load_lds(
        (const __attribute__((address_space(1))) void*)gA,
        (__attribute__((address_space(3))) void*)((char*)As[buf] + w * 1024), 16, 0, 0);
    __builtin_amdgcn_global_load_lds(
        (const __attribute__((address_space(1))) void*)gB,
        (__attribute__((address_space(3))) void*)((char*)Bs[buf] + w * 1024), 16, 0, 0);
  };

  const int nk = K >> 5;
  stage(0, 0);
  __syncthreads();
  int cur = 0;
  for (int t = 0; t < nk; ++t) {
    if (t + 1 < nk) stage(cur ^ 1, (t + 1) << 5);
    s16x8 af[2], bfr[2];
    #pragma unroll
    for (int mi = 0; mi < 2; ++mi) {
      int row = wr * 32 + mi * 16 + r16;
      af[mi] = *(const s16x8*)((const char*)As[cur] + swz(row * 64 + kc * 16));
    }
    #pragma unroll
    for (int ni = 0; ni < 2; ++ni) {
      int row = wc * 32 + ni * 16 + r16;
      bfr[ni] = *(const s16x8*)((const char*)Bs[cur] + swz(row * 64 + kc * 16));
    }
    #pragma unroll
    for (int mi = 0; mi < 2; ++mi)
      #pragma unroll
      for (int ni = 0; ni < 2; ++ni)
        acc[mi][ni] = __builtin_amdgcn_mfma_f32_16x16x32_bf16(af[mi], bfr[ni], acc[mi][ni], 0, 0, 0);
    __syncthreads();
    cur ^= 1;
  }

  #pragma unroll
  for (int mi = 0; mi < 2; ++mi) {
    #pragma unroll
    for (int ni = 0; ni < 2; ++ni) {
      int col = n0 + wc * 32 + ni * 16 + r16;
      #pragma unroll
      for (int j = 0; j < 4; ++j) {
        int rowg = m0 + wr * 32 + mi * 16 + kc * 4 + j;
        size_t idx = (size_t)rowg * N + col;
        float v = acc[mi][ni][j];
        if (EPI == 1) Cf[idx] += v;
        else {
          float t = v + bias[col];
          Cf[idx] = (t > 20.f) ? t : log1pf(__expf(t));
        }
      }
    }
  }
}

// ---------------------------------------------------------------------------
// Depthwise causal conv (k=4) + bias + silu -> ubf. xz bf16 (NTOK, 3072).
// ---------------------------------------------------------------------------
__global__ __launch_bounds__(256) void conv_silu_kernel(
    const bf16* __restrict__ xzb, const float* __restrict__ cw, const float* __restrict__ cb,
    bf16* __restrict__ ubf) {
  int m = blockIdx.x;
  int d = blockIdx.y * 256 + threadIdx.x;
  int s = m & (SEQ - 1);
  float acc = cb[d];
  #pragma unroll
  for (int j = 0; j < D_CONV; ++j) {
    int sj = s - 3 + j;
    if (sj >= 0) acc += bf2f(xzb[(size_t)(m - 3 + j) * (2 * D_INNER) + d]) * cw[d * D_CONV + j];
  }
  float sv = acc / (1.f + __expf(-acc));
  ubf[(size_t)m * D_INNER + d] = __float2bfloat16(sv);
}

// ---------------------------------------------------------------------------
// x_proj as skinny MFMA GEMM: xdbl[M=2048, 80] = ubf @ xpwT^T (xpwT (80,1536)).
// Block = 16 tokens; 4 waves split K (each 384, 12 K-steps x 5 MFMA);
// cross-wave reduce in LDS. Also emits dlt bf16 zero-padded to (NTOK, 64).
// ---------------------------------------------------------------------------
__global__ __launch_bounds__(256) void xproj_mfma_kernel(
    const bf16* __restrict__ ubf, const bf16* __restrict__ xpwT,
    float* __restrict__ xdbl, bf16* __restrict__ dltb) {
  const int m0 = blockIdx.x * 16;
  const int tid = threadIdx.x, lane = tid & 63, w = tid >> 6;
  const int r16 = lane & 15, kc = lane >> 4;
  __shared__ float part[4][16][80];  // 20 KB

  f32x4 acc[5];
  #pragma unroll
  for (int ni = 0; ni < 5; ++ni) acc[ni] = (f32x4){0.f, 0.f, 0.f, 0.f};

  const char* aBase = (const char*)ubf + (size_t)(m0 + r16) * 3072;
  #pragma unroll 4
  for (int kk = 0; kk < 12; ++kk) {
    int koff = (w * 384 + kk * 32) * 2 + kc * 16;
    s16x8 a = *(const s16x8*)(aBase + koff);
    #pragma unroll
    for (int ni = 0; ni < 5; ++ni) {
      s16x8 b = *(const s16x8*)((const char*)xpwT + (size_t)(ni * 16 + r16) * 3072 + koff);
      acc[ni] = __builtin_amdgcn_mfma_f32_16x16x32_bf16(a, b, acc[ni], 0, 0, 0);
    }
  }
  #pragma unroll
  for (int ni = 0; ni < 5; ++ni)
    #pragma unroll
    for (int j = 0; j < 4; ++j)
      part[w][kc * 4 + j][ni * 16 + r16] = acc[ni][j];
  __syncthreads();

  for (int i = tid; i < 16 * 80; i += 256) {
    int row = i / 80, col = i - row * 80;
    float s = part[0][row][col] + part[1][row][col] +
              part[2][row][col] + part[3][row][col];
    xdbl[(size_t)(m0 + row) * 80 + col] = s;
    if (col < DT_RANK) dltb[(size_t)(m0 + row) * 64 + col] = __float2bfloat16(s);
  }
  {  // zero-pad dlt cols 48..63 (16x16 = 256 elems, one per thread)
    int row = tid >> 4, k = DT_RANK + (tid & 15);
    dltb[(size_t)(m0 + row) * 64 + k] = __float2bfloat16(0.f);
  }
}

// ---------------------------------------------------------------------------
// Chunked parallel selective scan, LDS-staged (r13/r14 structure, verified).
// PASS 0: from x=0, chunk summary (Aprod, xpart).
// PASS 1: fold chunk-prefix inline, then emit y*silu(res); per-step 16-lane
// reduction via pure-VALU DPP butterfly (row16_sum).
// ---------------------------------------------------------------------------
template <int PASS>
__global__ __launch_bounds__(256) void scan_chunk_kernel(
    const float* __restrict__ delta, const bf16* __restrict__ ubf,
    const float* __restrict__ xdbl, const bf16* __restrict__ xzb,
    const float* __restrict__ A_log, const float* __restrict__ Dvec,
    float* __restrict__ Aprod, float* __restrict__ xpart,
    bf16* __restrict__ ybf) {
  int bd = blockIdx.x;  // 0 .. BATCH*96-1
  int c = blockIdx.y;
  int b = bd / (D_INNER / 16), dblk = bd % (D_INNER / 16);
  int grp = threadIdx.x >> 4, n = threadIdx.x & 15;
  int d = dblk * 16 + grp;
  const int d0 = dblk * 16;
  const size_t cstride = (size_t)BATCH * D_INNER * D_STATE;
  size_t si0 = ((size_t)b * D_INNER + d) * 16 + n;
  size_t mbase = (size_t)b * SEQ + (size_t)c * CHUNK;

  __shared__ float sd[CHUNK][16];                 // delta slice, 4KB
  __shared__ float su[CHUNK][16];                 // u slice, 4KB
  __shared__ float sB[CHUNK][16];                 // B_t, 4KB
  __shared__ float sC[PASS ? CHUNK : 1][16];      // C_t (pass1)
  __shared__ float sz[PASS ? CHUNK : 1][16];      // res (pass1)

  for (int i = threadIdx.x; i < CHUNK * 16; i += 256) {
    int t = i >> 4, dd = i & 15;
    size_t m = mbase + t;
    sd[t][dd] = delta[m * D_INNER + d0 + dd];
    su[t][dd] = bf2f(ubf[m * D_INNER + d0 + dd]);
    sB[t][dd] = xdbl[m * 80 + DT_RANK + dd];
    if (PASS == 1) {
      sC[t][dd] = xdbl[m * 80 + DT_RANK + D_STATE + dd];
      sz[t][dd] = bf2f(xzb[m * (2 * D_INNER) + D_INNER + d0 + dd]);
    }
  }
  __syncthreads();

  float Adn = -__expf(A_log[(size_t)d * D_STATE + n]);
  float Dd = Dvec[d];
  float xs = 0.f;
  if (PASS == 1) {
    for (int cc = 0; cc < c; ++cc)
      xs = fmaf(Aprod[cc * cstride + si0], xs, xpart[cc * cstride + si0]);
  }
  float ap = 1.f;
  #pragma unroll 4
  for (int t = 0; t < CHUNK; ++t) {
    float dlt = sd[t][grp];
    float uv = su[t][grp];
    float Bv = sB[t][n];
    float a = __expf(dlt * Adn);
    xs = fmaf(a, xs, dlt * Bv * uv);
    if (PASS == 0) {
      ap *= a;
    } else {
      float p = row16_sum(xs * sC[t][n]);
      if (n == 0) {
        float rv = sz[t][grp];
        float y = p + uv * Dd;
        float g = rv / (1.f + __expf(-rv));
        ybf[(mbase + t) * D_INNER + d] = __float2bfloat16(y * g);
      }
    }
  }
  if (PASS == 0) {
    Aprod[c * cstride + si0] = ap;
    xpart[c * cstride + si0] = xs;
  }
}

// ---------------------------------------------------------------------------
extern "C" void kernel_launch(void* const* d_in, const int* in_sizes, int n_in,
                              void* d_out, int out_size, void* d_ws, size_t ws_size,
                              hipStream_t stream) {
  const int* ids = (const int*)d_in[0];
  const float* emb = (const float*)d_in[1];     // (VOCAB, 768)
  const float* in_w = (const float*)d_in[2];    // (L, 768, 3072)
  const float* conv_w = (const float*)d_in[3];  // (L, 1536, 4)
  const float* conv_b = (const float*)d_in[4];  // (L, 1536)
  const float* xp_w = (const float*)d_in[5];    // (L, 1536, 80)
  const float* dt_w = (const float*)d_in[6];    // (L, 48, 1536)
  const float* dt_b = (const float*)d_in[7];    // (L, 1536)
  const float* A_log = (const float*)d_in[8];   // (L, 1536, 16)
  const float* Dv = (const float*)d_in[9];      // (L, 1536)
  const float* out_w = (const float*)d_in[10];  // (L, 1536, 768)
  const float* norm_w = (const float*)d_in[11]; // (L, 768)
  const float* norm_f = (const float*)d_in[12]; // (768)
  float* out = (float*)d_out;                   // (NTOK, VOCAB) f32

  // workspace carve
  char* p = (char*)d_ws;
  auto alloc = [&](size_t bytes) {
    char* r = p;
    p += (bytes + 255) & ~(size_t)255;
    return r;
  };
  float* x    = (float*)alloc((size_t)NTOK * D_MODEL * 4);
  bf16*  h    = (bf16*)alloc((size_t)NTOK * D_MODEL * 2);
  bf16*  xn   = (bf16*)alloc((size_t)NTOK * D_MODEL * 2);
  bf16*  xzb  = (bf16*)alloc((size_t)NTOK * 2 * D_INNER * 2);
  bf16*  ubf  = (bf16*)alloc((size_t)NTOK * D_INNER * 2);
  float* xdbl = (float*)alloc((size_t)NTOK * 80 * 4);
  bf16*  dltb = (bf16*)alloc((size_t)NTOK * 64 * 2);
  float* delta= (float*)alloc((size_t)NTOK * D_INNER * 4);
  bf16*  ybf  = (bf16*)alloc((size_t)NTOK * D_INNER * 2);
  float* Aprod= (float*)alloc((size_t)NCHUNK * BATCH * D_INNER * D_STATE * 4);
  float* xpart= (float*)alloc((size_t)NCHUNK * BATCH * D_INNER * D_STATE * 4);
  bf16*  in_wT  = (bf16*)alloc((size_t)N_LAYER * 2 * D_INNER * D_MODEL * 2);
  bf16*  out_wT = (bf16*)alloc((size_t)N_LAYER * D_MODEL * D_INNER * 2);
  bf16*  xp_wT  = (bf16*)alloc((size_t)N_LAYER * 80 * D_INNER * 2);
  bf16*  dt_wT  = (bf16*)alloc((size_t)N_LAYER * D_INNER * 64 * 2);
  bf16*  emb_bf = (bf16*)alloc((size_t)VOCAB * D_MODEL * 2);

  // Weight prep
  dim3 tb(32, 8);
  convert_f32_bf16_kernel<<<8192, 256, 0, stream>>>(
      emb, emb_bf, (long)VOCAB * D_MODEL / 4);
  transpose_f32_bf16_kernel<<<dim3(3072 / 32, 768 / 32, N_LAYER), tb, 0, stream>>>(
      in_w, in_wT, D_MODEL, 2 * D_INNER, D_MODEL);
  transpose_f32_bf16_kernel<<<dim3(768 / 32, 1536 / 32, N_LAYER), tb, 0, stream>>>(
      out_w, out_wT, D_INNER, D_MODEL, D_INNER);
  transpose_f32_bf16_kernel<<<dim3(3, 1536 / 32, N_LAYER), tb, 0, stream>>>(
      xp_w, xp_wT, D_INNER, 80, D_INNER);
  // dt_w (48,1536) -> (1536,64) zero-padded
  transpose_f32_bf16_kernel<<<dim3(1536 / 32, 2, N_LAYER), tb, 0, stream>>>(
      dt_w, dt_wT, DT_RANK, D_INNER, 64);

  embed_kernel<<<NTOK, 256, 0, stream>>>(ids, emb, x);

  for (int l = 0; l < N_LAYER; ++l) {
    const bf16* inwT_l = in_wT + (size_t)l * 2 * D_INNER * D_MODEL;
    const bf16* outwT_l = out_wT + (size_t)l * D_MODEL * D_INNER;
    const bf16* xpwT_l = xp_wT + (size_t)l * 80 * D_INNER;
    const bf16* dtwT_l = dt_wT + (size_t)l * D_INNER * 64;
    const float* Al = A_log + (size_t)l * D_INNER * D_STATE;
    const float* Dl = Dv + (size_t)l * D_INNER;

    rmsnorm_kernel<<<NTOK, 256, 0, stream>>>(x, norm_w + (size_t)l * D_MODEL, h);

    // in_proj: 128x128 counted-vmcnt GEMM, bf16 store into xzb
    gemm128_kernel<3><<<(NTOK / 128) * (2 * D_INNER / 128), 256, 0, stream>>>(
        h, inwT_l, nullptr, xzb, NTOK, 2 * D_INNER, D_MODEL);

    conv_silu_kernel<<<dim3(NTOK, D_INNER / 256), 256, 0, stream>>>(
        xzb, conv_w + (size_t)l * D_INNER * D_CONV, conv_b + (size_t)l * D_INNER, ubf);

    xproj_mfma_kernel<<<NTOK / 16, 256, 0, stream>>>(ubf, xpwT_l, xdbl, dltb);

    gemm64_kernel<2><<<(NTOK / 64) * (D_INNER / 64), 256, 0, stream>>>(
        dltb, dtwT_l, delta, dt_b + (size_t)l * D_INNER, NTOK, D_INNER, 64);

    dim3 sgrid(BATCH * (D_INNER / 16), NCHUNK);
    scan_chunk_kernel<0><<<sgrid, 256, 0, stream>>>(
        delta, ubf, xdbl, xzb, Al, Dl, Aprod, xpart, nullptr);
    scan_chunk_kernel<1><<<sgrid, 256, 0, stream>>>(
        delta, ubf, xdbl, xzb, Al, Dl, Aprod, xpart, ybf);

    gemm64_kernel<1><<<(NTOK / 64) * (D_MODEL / 64), 256, 0, stream>>>(
        ybf, outwT_l, x, nullptr, NTOK, D_MODEL, D_INNER);
  }

  rmsnorm_kernel<<<NTOK, 256, 0, stream>>>(x, norm_f, xn);

  gemm128_kernel<0><<<(NTOK / 128) * ((VOCAB + 127) / 128), 256, 0, stream>>>(
      xn, emb_bf, out, nullptr, NTOK, VOCAB, D_MODEL);
}